// Round 7
// baseline (339.975 us; speedup 1.0000x reference)
//
#include <hip/hip_runtime.h>
#include <hip/hip_bf16.h>

#define BATCH 16384
#define HID   1024
#define EMBD  512
#define NOPS  8
#define MAXT  136   // max tile slots: sum ceil(cnt_e/128) <= 135
#define CNTS  16    // cnt stride in ints (64 B) — one cache line per expert

typedef __attribute__((ext_vector_type(8))) short bf16x8;
typedef __attribute__((ext_vector_type(4))) float f32x4;

__device__ __forceinline__ unsigned short f2bf(float f) {
  unsigned int u = __float_as_uint(f);
  u += 0x7FFF + ((u >> 16) & 1);
  return (unsigned short)(u >> 16);
}

__device__ __forceinline__ unsigned int pk2(float a, float b) {
  __hip_bfloat162 t = __float22bfloat162_rn(make_float2(a, b));
  return *(unsigned int*)(&t);
}

__device__ __forceinline__ void lds_load16(void* lds, const void* g) {
  __builtin_amdgcn_global_load_lds(
      (const __attribute__((address_space(1))) unsigned int*)g,
      (__attribute__((address_space(3))) unsigned int*)lds, 16, 0, 0);
}

// XCD-locality decode: linear blocks round-robin across 8 XCDs, so bid&7 is
// the XCD. All 8 nx-blocks of a g land on one XCD (A-slab L2 reuse), and each
// XCD covers contiguous g-range [17c, 17c+17) ~= one expert (W-slab in L2).
__device__ __forceinline__ void decode_bid(int bid, int& g, int& nx) {
  g = 17 * (bid & 7) + (bid >> 6);
  nx = (bid >> 3) & 7;
}

// LDS-free weight transpose tile: lane reads along contiguous n (coalesced),
// 16 strided k-loads, packs bf16 in regs, writes 32-k half-row as two uint4.
// Wp slab: [128 n][32 k] bf16 where value = W[ks*32+k][nx*128+n].
__device__ __forceinline__ void w_prep_tile(const float* __restrict__ W,
                                            short* __restrict__ Wp,
                                            int ks, int nx, int tid) {
  int n = tid & 127, kh = tid >> 7;           // kh: low/high 16 of the 32-k tile
  const float* src = W + (size_t)(ks * 32 + kh * 16) * 1024 + nx * 128 + n;
  float v[16];
#pragma unroll
  for (int kk = 0; kk < 16; ++kk) v[kk] = src[(size_t)kk * 1024];
  uint4 a, b;
  a.x = pk2(v[0], v[1]);  a.y = pk2(v[2], v[3]);
  a.z = pk2(v[4], v[5]);  a.w = pk2(v[6], v[7]);
  b.x = pk2(v[8], v[9]);  b.y = pk2(v[10], v[11]);
  b.z = pk2(v[12], v[13]); b.w = pk2(v[14], v[15]);
  uint4* dst = (uint4*)(Wp + (size_t)n * 32);
  dst[kh * 2] = a;
  dst[kh * 2 + 1] = b;
}

// ---------------- phase 0: bucket (64) + W1 prep (2048) + ce (32) ------------
// ce[e][n] = b1[e][n] + sum_k emb[e][k] * W1[e][1024+k][n]  — the embedding
// half of GEMM1 collapses to a per-(expert,n) constant since every row of a
// tile shares the expert. Cuts GEMM1 K from 1536 to 1024.
__global__ void bucket_w1_k(const int* __restrict__ ops, int* __restrict__ cnt,
                            int* __restrict__ idx, const float* __restrict__ W1,
                            short* __restrict__ W1p, const float* __restrict__ emb,
                            const float* __restrict__ b1, float* __restrict__ ce) {
  int bid = blockIdx.x;
  int tid = threadIdx.x;
  if (bid >= 64 && bid < 64 + 2048) {
    // ---- W1 path: 8 e * 8 nx * 32 ks (first 1024 rows only) ----
    int b = bid - 64;
    int e = b / 256; int r = b % 256; int nx = r / 32, ks = r % 32;
    w_prep_tile(W1 + (size_t)e * 1536 * 1024,
                W1p + ((size_t)(e * 8 + nx) * 32 + ks) * 4096, ks, nx, tid);
    return;
  }
  if (bid >= 64 + 2048) {
    // ---- ce path: 32 blocks, each 256 outputs ----
    __shared__ float se[EMBD];
    int b2 = bid - 64 - 2048;
    int e = b2 >> 2, part = b2 & 3;
    int n = part * 256 + tid;
    se[tid] = emb[e * EMBD + tid];
    se[tid + 256] = emb[e * EMBD + tid + 256];
    __syncthreads();
    const float* Wc = W1 + (size_t)e * 1536 * 1024 + (size_t)1024 * 1024 + n;
    float acc = b1[e * HID + n];
#pragma unroll 8
    for (int k = 0; k < EMBD; ++k) acc += se[k] * Wc[(size_t)k * 1024];
    ce[e * HID + n] = acc;
    return;
  }
  // ---- bucket path (block-aggregated atomics) ----
  __shared__ int wcnt[4][NOPS];
  __shared__ int wbase[4][NOPS];
  int lane = tid & 63, w = tid >> 6;
  int t = bid * 256 + tid;
  int op = ops[t];
  unsigned long long msave = 0;
#pragma unroll
  for (int o = 0; o < NOPS; ++o) {
    unsigned long long mm = __ballot(op == o);
    if (op == o) msave = mm;
    if (lane == o) wcnt[w][o] = __popcll(mm);
  }
  __syncthreads();
  if (tid < NOPS) {
    int c0 = wcnt[0][tid], c1 = wcnt[1][tid], c2 = wcnt[2][tid], c3 = wcnt[3][tid];
    int base = atomicAdd(&cnt[tid * CNTS], c0 + c1 + c2 + c3);
    wbase[0][tid] = base;
    wbase[1][tid] = base + c0;
    wbase[2][tid] = base + c0 + c1;
    wbase[3][tid] = base + c0 + c1 + c2;
  }
  __syncthreads();
  int pre = __popcll(msave & ((1ull << lane) - 1ull));
  idx[op * BATCH + wbase[w][op] + pre] = t;
}

// build tile descriptors + pad index lists to tile multiples
__global__ void schedule_k(const int* __restrict__ cnt, int* __restrict__ desc,
                           int* __restrict__ ntp, int* __restrict__ idx) {
  if (threadIdx.x == 0) {
    int n = 0;
    for (int e = 0; e < NOPS; ++e) {
      int c = cnt[e * CNTS];
      for (int t = 0; t < c; t += 128) { desc[2 * n] = e; desc[2 * n + 1] = t; ++n; }
    }
    *ntp = n;
  }
  for (int e = 0; e < NOPS; ++e) {
    int c = cnt[e * CNTS];
    int cp = (c + 127) & ~127;
    for (int p = c + (int)threadIdx.x; p < cp; p += 256) idx[e * BATCH + p] = 0;
  }
}

// ---------------- phase 1: gather + convert + pre-tile A = x rows ------------
// Ap slab (g, ks): [128 r][32 k] bf16, rows are the tile's gathered tokens.
__global__ void prep_a_k(const float* __restrict__ x,
                         const int* __restrict__ idx, const int* __restrict__ desc,
                         const int* __restrict__ ntp, short* __restrict__ Ap) {
  __shared__ int toks[128];
  int bid = blockIdx.x;
  int g = bid >> 3, kx = bid & 7;
  if (g >= *ntp) return;
  int e = desc[2 * g], rs = desc[2 * g + 1];
  int tid = threadIdx.x;
  if (tid < 128) toks[tid] = idx[e * BATCH + rs + tid];
  __syncthreads();
  int r = tid >> 1, ah = tid & 1;
  int tok = toks[r];
  short* dst0 = Ap + (size_t)g * 32 * 4096;
#pragma unroll
  for (int kk = 0; kk < 4; ++kk) {
    int ks = kx * 4 + kk;
    const float* src = x + (size_t)tok * HID + ks * 32 + ah * 16;
    float4 f0 = ((const float4*)src)[0];
    float4 f1 = ((const float4*)src)[1];
    float4 f2v = ((const float4*)src)[2];
    float4 f3 = ((const float4*)src)[3];
    uint4 p0 = make_uint4(pk2(f0.x, f0.y), pk2(f0.z, f0.w), pk2(f1.x, f1.y), pk2(f1.z, f1.w));
    uint4 p1 = make_uint4(pk2(f2v.x, f2v.y), pk2(f2v.z, f2v.w), pk2(f3.x, f3.y), pk2(f3.z, f3.w));
    short* dst = dst0 + ks * 4096 + r * 32 + ah * 16;
    ((uint4*)dst)[0] = p0;
    ((uint4*)dst)[1] = p1;
  }
}

// ---------------- phase 2: GEMM1 (1088 blocks) + W2 prep (2048 blocks) -------
// h = relu(x_tile @ W1[e][:1024] + ce[e]);  K = 1024 (32 iters).
// W2 conversion blocks co-resident with MFMA waves (different pipes).
__global__ __launch_bounds__(256) void gemm1_w2_k(
    const short* __restrict__ Ap, const float* __restrict__ ce,
    const short* __restrict__ W1p, unsigned short* __restrict__ hp,
    const int* __restrict__ desc, const int* __restrict__ ntp,
    const float* __restrict__ W2, short* __restrict__ W2p) {
  int bid = blockIdx.x;
  int tid = threadIdx.x;
  if (bid >= 8 * MAXT) {
    // ---- W2 path: 8 e * 8 nx * 32 ks ----
    int b = bid - 8 * MAXT;
    int e = b / 256; int r = b % 256; int nx = r / 32, ks = r % 32;
    w_prep_tile(W2 + (size_t)e * 1024 * 1024,
                W2p + ((size_t)(e * 8 + nx) * 32 + ks) * 4096, ks, nx, tid);
    return;
  }
  int g, nx;
  decode_bid(bid, g, nx);
  if (g >= *ntp) return;
  int e = desc[2 * g];

  __shared__ __align__(16) char smem[16384];
  short* lA = (short*)smem;
  short* lB = (short*)(smem + 8192);

  int lane = tid & 63, w = tid >> 6;
  int wm = w >> 1, wn = w & 1;
  int fr = lane & 15, fq = lane >> 4;

  const char* Asrc = (const char*)Ap + (size_t)g * 32 * 8192;
  const char* Bsrc = (const char*)W1p + (size_t)(e * 8 + nx) * 32 * 8192;

  f32x4 acc[4][4] = {};

  for (int ks = 0; ks < 32; ++ks) {
    const char* as = Asrc + ks * 8192;
    const char* bs = Bsrc + ks * 8192;
    lds_load16(smem + w * 1024, as + w * 1024 + lane * 16);
    lds_load16(smem + 4096 + w * 1024, as + 4096 + w * 1024 + lane * 16);
    lds_load16(smem + 8192 + w * 1024, bs + w * 1024 + lane * 16);
    lds_load16(smem + 12288 + w * 1024, bs + 4096 + w * 1024 + lane * 16);
    __syncthreads();

    bf16x8 af[4], bfr[4];
#pragma unroll
    for (int i = 0; i < 4; ++i)
      af[i] = *(const bf16x8*)&lA[(wm * 64 + i * 16 + fr) * 32 + fq * 8];
#pragma unroll
    for (int j = 0; j < 4; ++j)
      bfr[j] = *(const bf16x8*)&lB[(wn * 64 + j * 16 + fr) * 32 + fq * 8];
#pragma unroll
    for (int i = 0; i < 4; ++i)
#pragma unroll
      for (int j = 0; j < 4; ++j)
        acc[i][j] = __builtin_amdgcn_mfma_f32_16x16x32_bf16(af[i], bfr[j], acc[i][j], 0, 0, 0);
    __syncthreads();
  }

  // epilogue: +ce (bias incl. embedding term) + relu + bf16, coalesced via LDS.
  // hp layout: [g][ks2(32)][128 r][32 k] so gemm2 A-staging is contiguous.
  float bias[4];
#pragma unroll
  for (int j = 0; j < 4; ++j)
    bias[j] = ce[e * HID + nx * 128 + wn * 64 + j * 16 + fr];

  unsigned short* ls = (unsigned short*)smem;   // per-wave 1024 ushorts @ w*1024
  int lr = lane >> 2;
#pragma unroll
  for (int i = 0; i < 4; ++i) {
    __syncthreads();
#pragma unroll
    for (int j = 0; j < 4; ++j)
#pragma unroll
      for (int rg = 0; rg < 4; ++rg) {
        float v = acc[i][j][rg] + bias[j];
        v = v > 0.f ? v : 0.f;
        ls[w * 1024 + (fq * 4 + rg) * 64 + j * 16 + fr] = f2bf(v);
      }
    __syncthreads();
    int R = wm * 64 + i * 16 + lr;
#pragma unroll
    for (int s = 0; s < 2; ++s) {
      int ch = (lane & 3) + s * 4;
      int ks2 = nx * 4 + wn * 2 + (ch >> 2);
      uint4 val = *(const uint4*)&ls[w * 1024 + lr * 64 + ch * 8];
      *(uint4*)(hp + ((size_t)(g * 32 + ks2) * 128 + R) * 32 + (ch & 3) * 8) = val;
    }
  }
}

// ---------------- phase 3: GEMM2  out[tok] = relu(h @ W2[e] + b2[e]) ----------------
__global__ __launch_bounds__(256) void gemm2_k(
    const unsigned short* __restrict__ hp, const float* __restrict__ b2,
    const short* __restrict__ W2p, float* __restrict__ out,
    const int* __restrict__ idx, const int* __restrict__ cnt,
    const int* __restrict__ desc, const int* __restrict__ ntp) {
  int g, nx;
  decode_bid(blockIdx.x, g, nx);
  if (g >= *ntp) return;
  int e = desc[2 * g], rs = desc[2 * g + 1];
  int ce2 = cnt[e * CNTS];

  __shared__ __align__(16) char smem[16384];
  __shared__ int toks[128];
  short* lA = (short*)smem;
  short* lB = (short*)(smem + 8192);

  int tid = threadIdx.x, lane = tid & 63, w = tid >> 6;
  int wm = w >> 1, wn = w & 1;
  int fr = lane & 15, fq = lane >> 4;

  if (tid < 128) toks[tid] = idx[e * BATCH + rs + tid];

  const char* Asrc = (const char*)hp + (size_t)g * 32 * 8192;
  const char* Bsrc = (const char*)W2p + (size_t)(e * 8 + nx) * 32 * 8192;

  f32x4 acc[4][4] = {};

  for (int ks = 0; ks < 32; ++ks) {
    const char* as = Asrc + ks * 8192;
    const char* bs = Bsrc + ks * 8192;
    lds_load16(smem + w * 1024, as + w * 1024 + lane * 16);
    lds_load16(smem + 4096 + w * 1024, as + 4096 + w * 1024 + lane * 16);
    lds_load16(smem + 8192 + w * 1024, bs + w * 1024 + lane * 16);
    lds_load16(smem + 12288 + w * 1024, bs + 4096 + w * 1024 + lane * 16);
    __syncthreads();

    bf16x8 af[4], bfr[4];
#pragma unroll
    for (int i = 0; i < 4; ++i)
      af[i] = *(const bf16x8*)&lA[(wm * 64 + i * 16 + fr) * 32 + fq * 8];
#pragma unroll
    for (int j = 0; j < 4; ++j)
      bfr[j] = *(const bf16x8*)&lB[(wn * 64 + j * 16 + fr) * 32 + fq * 8];
#pragma unroll
    for (int i = 0; i < 4; ++i)
#pragma unroll
      for (int j = 0; j < 4; ++j)
        acc[i][j] = __builtin_amdgcn_mfma_f32_16x16x32_bf16(af[i], bfr[j], acc[i][j], 0, 0, 0);
    __syncthreads();
  }

  // epilogue: bias + relu + scatter to out rows, coalesced via LDS round-trip.
  float bias[4];
#pragma unroll
  for (int j = 0; j < 4; ++j)
    bias[j] = b2[e * HID + nx * 128 + wn * 64 + j * 16 + fr];

  float* lsf = (float*)smem;                    // per-wave 1024 floats @ w*1024
  int lr = lane >> 2;
#pragma unroll
  for (int i = 0; i < 4; ++i) {
    __syncthreads();
#pragma unroll
    for (int j = 0; j < 4; ++j)
#pragma unroll
      for (int rg = 0; rg < 4; ++rg) {
        float v = acc[i][j][rg] + bias[j];
        lsf[w * 1024 + (fq * 4 + rg) * 64 + j * 16 + fr] = v > 0.f ? v : 0.f;
      }
    __syncthreads();
    int R = wm * 64 + i * 16 + lr;
    if (R < ce2 - rs) {
      float* orow = out + (size_t)toks[R] * HID + nx * 128 + wn * 64;
#pragma unroll
      for (int s = 0; s < 4; ++s) {
        int ch = (lane & 3) + s * 4;
        *(float4*)(orow + ch * 4) = *(const float4*)&lsf[w * 1024 + lr * 64 + ch * 4];
      }
    }
  }
}

// ---------------- workspace layout (bytes) ----------------
// cnt     @ 0          (512)
// ntiles  @ 1024       (4)
// desc    @ 1280       (1088)
// idx     @ 4096       (524288)       -> 528384
// W1p     @ 528384     (16777216)     -> 17305600
// W2p     @ 17305600   (16777216)     -> 34082816
// ce      @ 34082816   (32768)        -> 34115584
// hp      @ 34115584   (35651584)     -> 69767168
// Ap      @ 69767168   (35651584)     -> 105418752 (~105.4 MB)

extern "C" void kernel_launch(void* const* d_in, const int* in_sizes, int n_in,
                              void* d_out, int out_size, void* d_ws, size_t ws_size,
                              hipStream_t stream) {
  const float* x   = (const float*)d_in[0];
  const int*   ops = (const int*)d_in[1];
  const float* emb = (const float*)d_in[2];
  const float* W1  = (const float*)d_in[3];
  const float* b1  = (const float*)d_in[4];
  const float* W2  = (const float*)d_in[5];
  const float* b2  = (const float*)d_in[6];
  float* out = (float*)d_out;

  char* ws = (char*)d_ws;
  int* cnt  = (int*)(ws + 0);
  int* ntp  = (int*)(ws + 1024);
  int* desc = (int*)(ws + 1280);
  int* idx  = (int*)(ws + 4096);
  short* W1p = (short*)(ws + 528384);
  short* W2p = (short*)(ws + 17305600);
  float* ce  = (float*)(ws + 34082816);
  unsigned short* hp = (unsigned short*)(ws + 34115584);
  short* Ap = (short*)(ws + 69767168);

  hipMemsetAsync(cnt, 0, 512, stream);
  bucket_w1_k<<<64 + 2048 + 32, 256, 0, stream>>>(ops, cnt, idx, W1, W1p, emb, b1, ce);
  schedule_k<<<1, 256, 0, stream>>>(cnt, desc, ntp, idx);
  prep_a_k<<<8 * MAXT, 256, 0, stream>>>(x, idx, desc, ntp, Ap);
  gemm1_w2_k<<<8 * MAXT + 2048, 256, 0, stream>>>(Ap, ce, W1p, hp, desc, ntp, W2, W2p);
  gemm2_k<<<8 * MAXT, 256, 0, stream>>>(hp, b2, W2p, out, idx, cnt, desc, ntp);
}

// Round 8
// 303.377 us; speedup vs baseline: 1.1206x; 1.1206x over previous
//
#include <hip/hip_runtime.h>
#include <hip/hip_bf16.h>

#define BATCH 16384
#define HID   1024
#define EMBD  512
#define NOPS  8
#define MAXT  136   // max tile slots: sum ceil(cnt_e/128) <= 135
#define CNTS  16    // cnt stride in ints (64 B) — one cache line per expert

typedef __attribute__((ext_vector_type(8))) short bf16x8;
typedef __attribute__((ext_vector_type(4))) float f32x4;

__device__ __forceinline__ unsigned short f2bf(float f) {
  unsigned int u = __float_as_uint(f);
  u += 0x7FFF + ((u >> 16) & 1);
  return (unsigned short)(u >> 16);
}

__device__ __forceinline__ unsigned int pk2(float a, float b) {
  __hip_bfloat162 t = __float22bfloat162_rn(make_float2(a, b));
  return *(unsigned int*)(&t);
}

__device__ __forceinline__ void lds_load16(void* lds, const void* g) {
  __builtin_amdgcn_global_load_lds(
      (const __attribute__((address_space(1))) unsigned int*)g,
      (__attribute__((address_space(3))) unsigned int*)lds, 16, 0, 0);
}

// XCD-locality decode: linear blocks round-robin across 8 XCDs, so bid&7 is
// the XCD. All 8 nx-blocks of a g land on one XCD (A-slab L2 reuse), and each
// XCD covers contiguous g-range [17c, 17c+17) ~= one expert (W-slab in L2).
__device__ __forceinline__ void decode_bid(int bid, int& g, int& nx) {
  g = 17 * (bid & 7) + (bid >> 6);
  nx = (bid >> 3) & 7;
}

// LDS-free weight transpose tile: lane reads along contiguous n (coalesced),
// 16 strided k-loads, packs bf16 in regs, writes 32-k half-row as two uint4.
// Wp slab: [128 n][32 k] bf16 where value = W[ks*32+k][nx*128+n].
__device__ __forceinline__ void w_prep_tile(const float* __restrict__ W,
                                            short* __restrict__ Wp,
                                            int ks, int nx, int tid) {
  int n = tid & 127, kh = tid >> 7;           // kh: low/high 16 of the 32-k tile
  const float* src = W + (size_t)(ks * 32 + kh * 16) * 1024 + nx * 128 + n;
  float v[16];
#pragma unroll
  for (int kk = 0; kk < 16; ++kk) v[kk] = src[(size_t)kk * 1024];
  uint4 a, b;
  a.x = pk2(v[0], v[1]);  a.y = pk2(v[2], v[3]);
  a.z = pk2(v[4], v[5]);  a.w = pk2(v[6], v[7]);
  b.x = pk2(v[8], v[9]);  b.y = pk2(v[10], v[11]);
  b.z = pk2(v[12], v[13]); b.w = pk2(v[14], v[15]);
  uint4* dst = (uint4*)(Wp + (size_t)n * 32);
  dst[kh * 2] = a;
  dst[kh * 2 + 1] = b;
}

// ---------------- phase 0: ce (128 blocks) + bucket (64 blocks) --------------
// ce[e][n] = b1[e][n] + sum_k emb[e][k] * W1[e][1024+k][n]  — the embedding
// half of GEMM1 collapses to a per-(expert,n) constant (rows of a tile share
// the expert), cutting GEMM1 K from 1536 to 1024. ce must be memset-0 first;
// b1 folded by the kp==0 slice. 8e*16 k-slices, fp32 atomicAdd combine.
__global__ void bucket_ce_k(const int* __restrict__ ops, int* __restrict__ cnt,
                            int* __restrict__ idx, const float* __restrict__ W1,
                            const float* __restrict__ emb,
                            const float* __restrict__ b1, float* __restrict__ ce) {
  int bid = blockIdx.x;
  int tid = threadIdx.x;
  if (bid < 128) {
    // ---- ce path ----
    int e = bid >> 4, kp = bid & 15;
    int n = tid * 4;
    const float* Wc = W1 + (size_t)e * 1536 * 1024 + (size_t)(1024 + kp * 32) * 1024 + n;
    const float* ee = emb + e * EMBD + kp * 32;
    float4 a = make_float4(0.f, 0.f, 0.f, 0.f);
#pragma unroll
    for (int kk = 0; kk < 32; ++kk) {
      float s = ee[kk];
      float4 r = *(const float4*)(Wc + (size_t)kk * 1024);
      a.x += s * r.x; a.y += s * r.y; a.z += s * r.z; a.w += s * r.w;
    }
    if (kp == 0) {
      float4 b = *(const float4*)(b1 + e * HID + n);
      a.x += b.x; a.y += b.y; a.z += b.z; a.w += b.w;
    }
    float* d = ce + e * HID + n;
    atomicAdd(d + 0, a.x); atomicAdd(d + 1, a.y);
    atomicAdd(d + 2, a.z); atomicAdd(d + 3, a.w);
    return;
  }
  // ---- bucket path (block-aggregated atomics) ----
  __shared__ int wcnt[4][NOPS];
  __shared__ int wbase[4][NOPS];
  int lane = tid & 63, w = tid >> 6;
  int t = (bid - 128) * 256 + tid;
  int op = ops[t];
  unsigned long long msave = 0;
#pragma unroll
  for (int o = 0; o < NOPS; ++o) {
    unsigned long long mm = __ballot(op == o);
    if (op == o) msave = mm;
    if (lane == o) wcnt[w][o] = __popcll(mm);
  }
  __syncthreads();
  if (tid < NOPS) {
    int c0 = wcnt[0][tid], c1 = wcnt[1][tid], c2 = wcnt[2][tid], c3 = wcnt[3][tid];
    int base = atomicAdd(&cnt[tid * CNTS], c0 + c1 + c2 + c3);
    wbase[0][tid] = base;
    wbase[1][tid] = base + c0;
    wbase[2][tid] = base + c0 + c1;
    wbase[3][tid] = base + c0 + c1 + c2;
  }
  __syncthreads();
  int pre = __popcll(msave & ((1ull << lane) - 1ull));
  idx[op * BATCH + wbase[w][op] + pre] = t;
}

// build tile descriptors + pad index lists to tile multiples
__global__ void schedule_k(const int* __restrict__ cnt, int* __restrict__ desc,
                           int* __restrict__ ntp, int* __restrict__ idx) {
  if (threadIdx.x == 0) {
    int n = 0;
    for (int e = 0; e < NOPS; ++e) {
      int c = cnt[e * CNTS];
      for (int t = 0; t < c; t += 128) { desc[2 * n] = e; desc[2 * n + 1] = t; ++n; }
    }
    *ntp = n;
  }
  for (int e = 0; e < NOPS; ++e) {
    int c = cnt[e * CNTS];
    int cp = (c + 127) & ~127;
    for (int p = c + (int)threadIdx.x; p < cp; p += 256) idx[e * BATCH + p] = 0;
  }
}

// ---------------- phase 1: A-tiles (1088 blocks) + W1 prep (2048 blocks) -----
// W1 conversion has its deadline at gemm1, not schedule — so it rides here,
// overlapped with the A gather, keeping the pre-schedule critical path short.
// Ap slab (g, ks): [128 r][32 k] bf16, rows are the tile's gathered tokens.
__global__ void prep_k(const float* __restrict__ x,
                       const int* __restrict__ idx, const int* __restrict__ desc,
                       const int* __restrict__ ntp, short* __restrict__ Ap,
                       const float* __restrict__ W1, short* __restrict__ W1p) {
  int bid = blockIdx.x;
  int tid = threadIdx.x;
  if (bid >= 8 * MAXT) {
    // ---- W1 path: 8 e * 8 nx * 32 ks (first 1024 rows only) ----
    int b = bid - 8 * MAXT;
    int e = b / 256; int r = b % 256; int nx = r / 32, ks = r % 32;
    w_prep_tile(W1 + (size_t)e * 1536 * 1024,
                W1p + ((size_t)(e * 8 + nx) * 32 + ks) * 4096, ks, nx, tid);
    return;
  }
  // ---- A path ----
  __shared__ int toks[128];
  int g = bid >> 3, kx = bid & 7;
  if (g >= *ntp) return;
  int e = desc[2 * g], rs = desc[2 * g + 1];
  if (tid < 128) toks[tid] = idx[e * BATCH + rs + tid];
  __syncthreads();
  int r = tid >> 1, ah = tid & 1;
  int tok = toks[r];
  short* dst0 = Ap + (size_t)g * 32 * 4096;
#pragma unroll
  for (int kk = 0; kk < 4; ++kk) {
    int ks = kx * 4 + kk;
    const float* src = x + (size_t)tok * HID + ks * 32 + ah * 16;
    float4 f0 = ((const float4*)src)[0];
    float4 f1 = ((const float4*)src)[1];
    float4 f2v = ((const float4*)src)[2];
    float4 f3 = ((const float4*)src)[3];
    uint4 p0 = make_uint4(pk2(f0.x, f0.y), pk2(f0.z, f0.w), pk2(f1.x, f1.y), pk2(f1.z, f1.w));
    uint4 p1 = make_uint4(pk2(f2v.x, f2v.y), pk2(f2v.z, f2v.w), pk2(f3.x, f3.y), pk2(f3.z, f3.w));
    short* dst = dst0 + ks * 4096 + r * 32 + ah * 16;
    ((uint4*)dst)[0] = p0;
    ((uint4*)dst)[1] = p1;
  }
}

// ---------------- phase 2: GEMM1 (1088 blocks) + W2 prep (2048 blocks) -------
// h = relu(x_tile @ W1[e][:1024] + ce[e]);  K = 1024 (32 iters).
// W2 conversion blocks co-resident with MFMA waves (different pipes).
__global__ __launch_bounds__(256) void gemm1_w2_k(
    const short* __restrict__ Ap, const float* __restrict__ ce,
    const short* __restrict__ W1p, unsigned short* __restrict__ hp,
    const int* __restrict__ desc, const int* __restrict__ ntp,
    const float* __restrict__ W2, short* __restrict__ W2p) {
  int bid = blockIdx.x;
  int tid = threadIdx.x;
  if (bid >= 8 * MAXT) {
    // ---- W2 path: 8 e * 8 nx * 32 ks ----
    int b = bid - 8 * MAXT;
    int e = b / 256; int r = b % 256; int nx = r / 32, ks = r % 32;
    w_prep_tile(W2 + (size_t)e * 1024 * 1024,
                W2p + ((size_t)(e * 8 + nx) * 32 + ks) * 4096, ks, nx, tid);
    return;
  }
  int g, nx;
  decode_bid(bid, g, nx);
  if (g >= *ntp) return;
  int e = desc[2 * g];

  __shared__ __align__(16) char smem[16384];
  short* lA = (short*)smem;
  short* lB = (short*)(smem + 8192);

  int lane = tid & 63, w = tid >> 6;
  int wm = w >> 1, wn = w & 1;
  int fr = lane & 15, fq = lane >> 4;

  const char* Asrc = (const char*)Ap + (size_t)g * 32 * 8192;
  const char* Bsrc = (const char*)W1p + (size_t)(e * 8 + nx) * 32 * 8192;

  f32x4 acc[4][4] = {};

  for (int ks = 0; ks < 32; ++ks) {
    const char* as = Asrc + ks * 8192;
    const char* bs = Bsrc + ks * 8192;
    lds_load16(smem + w * 1024, as + w * 1024 + lane * 16);
    lds_load16(smem + 4096 + w * 1024, as + 4096 + w * 1024 + lane * 16);
    lds_load16(smem + 8192 + w * 1024, bs + w * 1024 + lane * 16);
    lds_load16(smem + 12288 + w * 1024, bs + 4096 + w * 1024 + lane * 16);
    __syncthreads();

    bf16x8 af[4], bfr[4];
#pragma unroll
    for (int i = 0; i < 4; ++i)
      af[i] = *(const bf16x8*)&lA[(wm * 64 + i * 16 + fr) * 32 + fq * 8];
#pragma unroll
    for (int j = 0; j < 4; ++j)
      bfr[j] = *(const bf16x8*)&lB[(wn * 64 + j * 16 + fr) * 32 + fq * 8];
#pragma unroll
    for (int i = 0; i < 4; ++i)
#pragma unroll
      for (int j = 0; j < 4; ++j)
        acc[i][j] = __builtin_amdgcn_mfma_f32_16x16x32_bf16(af[i], bfr[j], acc[i][j], 0, 0, 0);
    __syncthreads();
  }

  // epilogue: +ce (bias incl. embedding term) + relu + bf16, coalesced via LDS.
  // hp layout: [g][ks2(32)][128 r][32 k] so gemm2 A-staging is contiguous.
  float bias[4];
#pragma unroll
  for (int j = 0; j < 4; ++j)
    bias[j] = ce[e * HID + nx * 128 + wn * 64 + j * 16 + fr];

  unsigned short* ls = (unsigned short*)smem;   // per-wave 1024 ushorts @ w*1024
  int lr = lane >> 2;
#pragma unroll
  for (int i = 0; i < 4; ++i) {
    __syncthreads();
#pragma unroll
    for (int j = 0; j < 4; ++j)
#pragma unroll
      for (int rg = 0; rg < 4; ++rg) {
        float v = acc[i][j][rg] + bias[j];
        v = v > 0.f ? v : 0.f;
        ls[w * 1024 + (fq * 4 + rg) * 64 + j * 16 + fr] = f2bf(v);
      }
    __syncthreads();
    int R = wm * 64 + i * 16 + lr;
#pragma unroll
    for (int s = 0; s < 2; ++s) {
      int ch = (lane & 3) + s * 4;
      int ks2 = nx * 4 + wn * 2 + (ch >> 2);
      uint4 val = *(const uint4*)&ls[w * 1024 + lr * 64 + ch * 8];
      *(uint4*)(hp + ((size_t)(g * 32 + ks2) * 128 + R) * 32 + (ch & 3) * 8) = val;
    }
  }
}

// ---------------- phase 3: GEMM2  out[tok] = relu(h @ W2[e] + b2[e]) ----------------
__global__ __launch_bounds__(256) void gemm2_k(
    const unsigned short* __restrict__ hp, const float* __restrict__ b2,
    const short* __restrict__ W2p, float* __restrict__ out,
    const int* __restrict__ idx, const int* __restrict__ cnt,
    const int* __restrict__ desc, const int* __restrict__ ntp) {
  int g, nx;
  decode_bid(blockIdx.x, g, nx);
  if (g >= *ntp) return;
  int e = desc[2 * g], rs = desc[2 * g + 1];
  int ce2 = cnt[e * CNTS];

  __shared__ __align__(16) char smem[16384];
  __shared__ int toks[128];
  short* lA = (short*)smem;
  short* lB = (short*)(smem + 8192);

  int tid = threadIdx.x, lane = tid & 63, w = tid >> 6;
  int wm = w >> 1, wn = w & 1;
  int fr = lane & 15, fq = lane >> 4;

  if (tid < 128) toks[tid] = idx[e * BATCH + rs + tid];

  const char* Asrc = (const char*)hp + (size_t)g * 32 * 8192;
  const char* Bsrc = (const char*)W2p + (size_t)(e * 8 + nx) * 32 * 8192;

  f32x4 acc[4][4] = {};

  for (int ks = 0; ks < 32; ++ks) {
    const char* as = Asrc + ks * 8192;
    const char* bs = Bsrc + ks * 8192;
    lds_load16(smem + w * 1024, as + w * 1024 + lane * 16);
    lds_load16(smem + 4096 + w * 1024, as + 4096 + w * 1024 + lane * 16);
    lds_load16(smem + 8192 + w * 1024, bs + w * 1024 + lane * 16);
    lds_load16(smem + 12288 + w * 1024, bs + 4096 + w * 1024 + lane * 16);
    __syncthreads();

    bf16x8 af[4], bfr[4];
#pragma unroll
    for (int i = 0; i < 4; ++i)
      af[i] = *(const bf16x8*)&lA[(wm * 64 + i * 16 + fr) * 32 + fq * 8];
#pragma unroll
    for (int j = 0; j < 4; ++j)
      bfr[j] = *(const bf16x8*)&lB[(wn * 64 + j * 16 + fr) * 32 + fq * 8];
#pragma unroll
    for (int i = 0; i < 4; ++i)
#pragma unroll
      for (int j = 0; j < 4; ++j)
        acc[i][j] = __builtin_amdgcn_mfma_f32_16x16x32_bf16(af[i], bfr[j], acc[i][j], 0, 0, 0);
    __syncthreads();
  }

  // epilogue: bias + relu + scatter to out rows, coalesced via LDS round-trip.
  float bias[4];
#pragma unroll
  for (int j = 0; j < 4; ++j)
    bias[j] = b2[e * HID + nx * 128 + wn * 64 + j * 16 + fr];

  float* lsf = (float*)smem;                    // per-wave 1024 floats @ w*1024
  int lr = lane >> 2;
#pragma unroll
  for (int i = 0; i < 4; ++i) {
    __syncthreads();
#pragma unroll
    for (int j = 0; j < 4; ++j)
#pragma unroll
      for (int rg = 0; rg < 4; ++rg) {
        float v = acc[i][j][rg] + bias[j];
        lsf[w * 1024 + (fq * 4 + rg) * 64 + j * 16 + fr] = v > 0.f ? v : 0.f;
      }
    __syncthreads();
    int R = wm * 64 + i * 16 + lr;
    if (R < ce2 - rs) {
      float* orow = out + (size_t)toks[R] * HID + nx * 128 + wn * 64;
#pragma unroll
      for (int s = 0; s < 4; ++s) {
        int ch = (lane & 3) + s * 4;
        *(float4*)(orow + ch * 4) = *(const float4*)&lsf[w * 1024 + lr * 64 + ch * 4];
      }
    }
  }
}

// ---------------- workspace layout (bytes) ----------------
// cnt     @ 0          (512)          — zeroed (with ce) by one memset
// ce      @ 512        (32768)        -> 33280
// ntiles  @ 33280      (4)
// desc    @ 33344      (1088)         -> 34432
// idx     @ 36864      (524288)       -> 561152
// W1p     @ 561152     (16777216)     -> 17338368
// W2p     @ 17338368   (16777216)     -> 34115584
// hp      @ 34115584   (35651584)     -> 69767168
// Ap      @ 69767168   (35651584)     -> 105418752 (~105.4 MB)

extern "C" void kernel_launch(void* const* d_in, const int* in_sizes, int n_in,
                              void* d_out, int out_size, void* d_ws, size_t ws_size,
                              hipStream_t stream) {
  const float* x   = (const float*)d_in[0];
  const int*   ops = (const int*)d_in[1];
  const float* emb = (const float*)d_in[2];
  const float* W1  = (const float*)d_in[3];
  const float* b1  = (const float*)d_in[4];
  const float* W2  = (const float*)d_in[5];
  const float* b2  = (const float*)d_in[6];
  float* out = (float*)d_out;

  char* ws = (char*)d_ws;
  int* cnt  = (int*)(ws + 0);
  float* ce = (float*)(ws + 512);
  int* ntp  = (int*)(ws + 33280);
  int* desc = (int*)(ws + 33344);
  int* idx  = (int*)(ws + 36864);
  short* W1p = (short*)(ws + 561152);
  short* W2p = (short*)(ws + 17338368);
  unsigned short* hp = (unsigned short*)(ws + 34115584);
  short* Ap = (short*)(ws + 69767168);

  hipMemsetAsync(ws, 0, 33280, stream);   // cnt + ce
  bucket_ce_k<<<128 + 64, 256, 0, stream>>>(ops, cnt, idx, W1, emb, b1, ce);
  schedule_k<<<1, 256, 0, stream>>>(cnt, desc, ntp, idx);
  prep_k<<<8 * MAXT + 2048, 256, 0, stream>>>(x, idx, desc, ntp, Ap, W1, W1p);
  gemm1_w2_k<<<8 * MAXT + 2048, 256, 0, stream>>>(Ap, ce, W1p, hp, desc, ntp, W2, W2p);
  gemm2_k<<<8 * MAXT, 256, 0, stream>>>(hp, b2, W2p, out, idx, cnt, desc, ntp);
}